// Round 1
// baseline (724.411 us; speedup 1.0000x reference)
//
#include <hip/hip_runtime.h>
#include <math.h>

#define N_CELLS 100000
#define N_EDGES 1600000
#define FDIM 32
#define NEG_SLOPE 0.2f

__device__ __forceinline__ unsigned int float_to_ordered(float f) {
    unsigned int b = __float_as_uint(f);
    return (b & 0x80000000u) ? ~b : (b | 0x80000000u);
}
__device__ __forceinline__ float ordered_to_float(unsigned int u) {
    unsigned int b = (u & 0x80000000u) ? (u ^ 0x80000000u) : ~u;
    return __uint_as_float(b);
}

// Kernel 1: h_irr = x@Wirr, h_sol = x@Wsol, plus per-node attention scores.
// One 64-lane wave handles 2 rows (32 lanes per row, f = lane&31).
__global__ void k_h_scores(const float* __restrict__ x,
                           const float* __restrict__ Wirr, const float* __restrict__ Wsol,
                           const float* __restrict__ att_irr, const float* __restrict__ att_sol,
                           float* __restrict__ h_irr, float* __restrict__ h_sol,
                           float* __restrict__ s_src_irr, float* __restrict__ s_tgt_irr,
                           float* __restrict__ s_src_sol, float* __restrict__ s_tgt_sol) {
    __shared__ float sWirr[FDIM * FDIM], sWsol[FDIM * FDIM];
    __shared__ float sAi[2 * FDIM], sAs[2 * FDIM];
    int t = threadIdx.x;
    for (int i = t; i < FDIM * FDIM; i += blockDim.x) {
        sWirr[i] = Wirr[i];
        sWsol[i] = Wsol[i];
    }
    if (t < 2 * FDIM) { sAi[t] = att_irr[t]; sAs[t] = att_sol[t]; }
    __syncthreads();

    int wave_in_block = t >> 6;
    int lane = t & 63;
    int halfsel = lane >> 5;
    int f = lane & 31;
    int row = (blockIdx.x * (blockDim.x >> 6) + wave_in_block) * 2 + halfsel;
    if (row >= N_CELLS) return;

    const float* xr = x + (long long)row * FDIM;
    float hi = 0.f, hs = 0.f;
#pragma unroll
    for (int k = 0; k < FDIM; ++k) {
        float xv = xr[k];
        hi += xv * sWirr[k * FDIM + f];
        hs += xv * sWsol[k * FDIM + f];
    }
    h_irr[(long long)row * FDIM + f] = hi;
    h_sol[(long long)row * FDIM + f] = hs;

    float pi0 = hi * sAi[f], pi1 = hi * sAi[FDIM + f];
    float ps0 = hs * sAs[f], ps1 = hs * sAs[FDIM + f];
#pragma unroll
    for (int m = 16; m >= 1; m >>= 1) {
        pi0 += __shfl_xor(pi0, m);
        pi1 += __shfl_xor(pi1, m);
        ps0 += __shfl_xor(ps0, m);
        ps1 += __shfl_xor(ps1, m);
    }
    if (f == 0) {
        s_src_irr[row] = pi0;
        s_tgt_irr[row] = pi1;
        s_src_sol[row] = ps0;
        s_tgt_sol[row] = ps1;
    }
}

// Kernel 2: global max of leaky_relu(s_src[src]+s_tgt[tgt]) over all edges.
__global__ void k_edge_max(const int* __restrict__ src, const int* __restrict__ tgt,
                           const float* __restrict__ s_src, const float* __restrict__ s_tgt,
                           unsigned int* __restrict__ gmax_u) {
    int e = blockIdx.x * blockDim.x + threadIdx.x;
    float v = -INFINITY;
    if (e < N_EDGES) {
        float ev = s_src[src[e]] + s_tgt[tgt[e]];
        v = ev > 0.f ? ev : NEG_SLOPE * ev;
    }
#pragma unroll
    for (int m = 32; m >= 1; m >>= 1) v = fmaxf(v, __shfl_xor(v, m));
    __shared__ float smax[4];
    int lane = threadIdx.x & 63, w = threadIdx.x >> 6;
    if (lane == 0) smax[w] = v;
    __syncthreads();
    if (threadIdx.x == 0) {
        float b = fmaxf(fmaxf(smax[0], smax[1]), fmaxf(smax[2], smax[3]));
        atomicMax(gmax_u, float_to_ordered(b));
    }
}

// Kernel 3: exp_sum[src] += exp(e - gmax)
__global__ void k_exp_sum(const int* __restrict__ src, const int* __restrict__ tgt,
                          const float* __restrict__ s_src, const float* __restrict__ s_tgt,
                          const unsigned int* __restrict__ gmax_u,
                          float* __restrict__ exp_sum) {
    int e = blockIdx.x * blockDim.x + threadIdx.x;
    if (e >= N_EDGES) return;
    int s = src[e];
    float ev = s_src[s] + s_tgt[tgt[e]];
    ev = ev > 0.f ? ev : NEG_SLOPE * ev;
    float gmax = ordered_to_float(*gmax_u);
    atomicAdd(&exp_sum[s], expf(ev - gmax));
}

// Kernel 4: out[src] += (exp_v / (exp_sum[src]+1e-10)) * h[tgt]; 32 lanes per edge.
__global__ void k_aggregate(const int* __restrict__ src, const int* __restrict__ tgt,
                            const float* __restrict__ s_src, const float* __restrict__ s_tgt,
                            const float* __restrict__ h,
                            const unsigned int* __restrict__ gmax_u,
                            const float* __restrict__ exp_sum,
                            float* __restrict__ out) {
    long long tid = (long long)blockIdx.x * blockDim.x + threadIdx.x;
    long long e = tid >> 5;
    int f = (int)(tid & 31);
    if (e >= N_EDGES) return;
    int s = src[e], tg = tgt[e];
    float ev = s_src[s] + s_tgt[tg];
    ev = ev > 0.f ? ev : NEG_SLOPE * ev;
    float gmax = ordered_to_float(*gmax_u);
    float att = expf(ev - gmax) / (exp_sum[s] + 1e-10f);
    atomicAdd(&out[(long long)s * FDIM + f], att * h[(long long)tg * FDIM + f]);
}

// Kernel 5: in-place ELU on accumulated output.
__global__ void k_elu(float* __restrict__ out, int n) {
    int i = blockIdx.x * blockDim.x + threadIdx.x;
    if (i < n) {
        float v = out[i];
        out[i] = v > 0.f ? v : expf(v) - 1.f;
    }
}

extern "C" void kernel_launch(void* const* d_in, const int* in_sizes, int n_in,
                              void* d_out, int out_size, void* d_ws, size_t ws_size,
                              hipStream_t stream) {
    const float* x = (const float*)d_in[0];
    const int* do_index = (const int*)d_in[1];
    const int* up_index = (const int*)d_in[2];
    const float* Wirr = (const float*)d_in[3];
    const float* Wsol = (const float*)d_in[4];
    const float* att_irr = (const float*)d_in[5];
    const float* att_sol = (const float*)d_in[6];
    float* out = (float*)d_out;

    // Workspace partition (floats)
    float* ws = (float*)d_ws;
    float* h_irr = ws;                              // N*F
    float* h_sol = h_irr + (long long)N_CELLS * FDIM;  // N*F
    float* s_src_irr = h_sol + (long long)N_CELLS * FDIM;  // N
    float* s_tgt_irr = s_src_irr + N_CELLS;         // N
    float* s_src_sol = s_tgt_irr + N_CELLS;         // N
    float* s_tgt_sol = s_src_sol + N_CELLS;         // N
    float* exp_sum_irr = s_tgt_sol + N_CELLS;       // N
    float* exp_sum_sol = exp_sum_irr + N_CELLS;     // N
    unsigned int* gmax = (unsigned int*)(exp_sum_sol + N_CELLS);  // 2 uints

    const int* src_irr = do_index;
    const int* tgt_irr = do_index + N_EDGES;
    const int* src_sol = up_index;
    const int* tgt_sol = up_index + N_EDGES;

    // Zero accumulators (exp_sum_irr, exp_sum_sol, gmax contiguous) + output.
    hipMemsetAsync(exp_sum_irr, 0, (2 * (size_t)N_CELLS + 2) * sizeof(float), stream);
    hipMemsetAsync(d_out, 0, (size_t)N_CELLS * FDIM * sizeof(float), stream);

    // K1: h + scores (8 rows per 256-thread block)
    {
        int rows_per_block = (256 / 64) * 2;
        int grid = (N_CELLS + rows_per_block - 1) / rows_per_block;
        hipLaunchKernelGGL(k_h_scores, dim3(grid), dim3(256), 0, stream,
                           x, Wirr, Wsol, att_irr, att_sol,
                           h_irr, h_sol, s_src_irr, s_tgt_irr, s_src_sol, s_tgt_sol);
    }

    int egrid = (N_EDGES + 255) / 256;
    // K2: global max per branch
    hipLaunchKernelGGL(k_edge_max, dim3(egrid), dim3(256), 0, stream,
                       src_irr, tgt_irr, s_src_irr, s_tgt_irr, gmax);
    hipLaunchKernelGGL(k_edge_max, dim3(egrid), dim3(256), 0, stream,
                       src_sol, tgt_sol, s_src_sol, s_tgt_sol, gmax + 1);

    // K3: exp-sum per branch
    hipLaunchKernelGGL(k_exp_sum, dim3(egrid), dim3(256), 0, stream,
                       src_irr, tgt_irr, s_src_irr, s_tgt_irr, gmax, exp_sum_irr);
    hipLaunchKernelGGL(k_exp_sum, dim3(egrid), dim3(256), 0, stream,
                       src_sol, tgt_sol, s_src_sol, s_tgt_sol, gmax + 1, exp_sum_sol);

    // K4: aggregate per branch (32 lanes per edge)
    {
        long long total = (long long)N_EDGES * 32;
        int grid = (int)((total + 255) / 256);
        hipLaunchKernelGGL(k_aggregate, dim3(grid), dim3(256), 0, stream,
                           src_irr, tgt_irr, s_src_irr, s_tgt_irr, h_irr, gmax, exp_sum_irr, out);
        hipLaunchKernelGGL(k_aggregate, dim3(grid), dim3(256), 0, stream,
                           src_sol, tgt_sol, s_src_sol, s_tgt_sol, h_sol, gmax + 1, exp_sum_sol, out);
    }

    // K5: ELU in place
    {
        int n = N_CELLS * FDIM;
        int grid = (n + 255) / 256;
        hipLaunchKernelGGL(k_elu, dim3(grid), dim3(256), 0, stream, out, n);
    }
}

// Round 2
// 508.519 us; speedup vs baseline: 1.4245x; 1.4245x over previous
//
#include <hip/hip_runtime.h>
#include <math.h>

#define N_CELLS 100000
#define N_EDGES 1600000
#define FDIM 32
#define NEG_SLOPE 0.2f
#define NSEG (2 * N_CELLS)          // counts/offsets for both branches concatenated
#define SCAN_BLOCK 2048             // elements per scan block (256 thr x 8)
#define NSCAN_BLOCKS ((NSEG + SCAN_BLOCK - 1) / SCAN_BLOCK)   // 98
#define EDGE_BLOCKS ((2 * N_EDGES) / 256)                     // 12500 (exact)
#define BLOCKS_PER_BRANCH (N_EDGES / 256)                     // 6250 (exact)

// Kernel 1: h_irr = x@Wirr, h_sol = x@Wsol, plus per-node attention scores.
// One 64-lane wave handles 2 rows (32 lanes per row, f = lane&31).
__global__ void k_h_scores(const float* __restrict__ x,
                           const float* __restrict__ Wirr, const float* __restrict__ Wsol,
                           const float* __restrict__ att_irr, const float* __restrict__ att_sol,
                           float* __restrict__ h_irr, float* __restrict__ h_sol,
                           float* __restrict__ s_src_irr, float* __restrict__ s_tgt_irr,
                           float* __restrict__ s_src_sol, float* __restrict__ s_tgt_sol) {
    __shared__ float sWirr[FDIM * FDIM], sWsol[FDIM * FDIM];
    __shared__ float sAi[2 * FDIM], sAs[2 * FDIM];
    int t = threadIdx.x;
    for (int i = t; i < FDIM * FDIM; i += blockDim.x) {
        sWirr[i] = Wirr[i];
        sWsol[i] = Wsol[i];
    }
    if (t < 2 * FDIM) { sAi[t] = att_irr[t]; sAs[t] = att_sol[t]; }
    __syncthreads();

    int wave_in_block = t >> 6;
    int lane = t & 63;
    int halfsel = lane >> 5;
    int f = lane & 31;
    int row = (blockIdx.x * (blockDim.x >> 6) + wave_in_block) * 2 + halfsel;
    if (row >= N_CELLS) return;

    const float* xr = x + (long long)row * FDIM;
    float hi = 0.f, hs = 0.f;
#pragma unroll
    for (int k = 0; k < FDIM; ++k) {
        float xv = xr[k];
        hi += xv * sWirr[k * FDIM + f];
        hs += xv * sWsol[k * FDIM + f];
    }
    h_irr[(long long)row * FDIM + f] = hi;
    h_sol[(long long)row * FDIM + f] = hs;

    float pi0 = hi * sAi[f], pi1 = hi * sAi[FDIM + f];
    float ps0 = hs * sAs[f], ps1 = hs * sAs[FDIM + f];
#pragma unroll
    for (int m = 16; m >= 1; m >>= 1) {
        pi0 += __shfl_xor(pi0, m);
        pi1 += __shfl_xor(pi1, m);
        ps0 += __shfl_xor(ps0, m);
        ps1 += __shfl_xor(ps1, m);
    }
    if (f == 0) {
        s_src_irr[row] = pi0;
        s_tgt_irr[row] = pi1;
        s_src_sol[row] = ps0;
        s_tgt_sol[row] = ps1;
    }
}

// Kernel 2: histogram of src for both branches into counts[0..NSEG)
__global__ void k_count(const int* __restrict__ do_idx, const int* __restrict__ up_idx,
                        int* __restrict__ counts) {
    int tid = blockIdx.x * 256 + threadIdx.x;          // exact grid: 2*N_EDGES
    if (tid < N_EDGES) {
        atomicAdd(&counts[do_idx[tid]], 1);
    } else {
        atomicAdd(&counts[N_CELLS + up_idx[tid - N_EDGES]], 1);
    }
}

// Scan a: per-block exclusive scan of counts (2048 elems/block) + block sums.
__global__ void k_scan_a(const int* __restrict__ counts, int* __restrict__ offsets,
                         int* __restrict__ blksums) {
    __shared__ int sdata[256];
    int t = threadIdx.x;
    int base = blockIdx.x * SCAN_BLOCK + t * 8;
    int v[8];
    int sum = 0;
#pragma unroll
    for (int j = 0; j < 8; ++j) {
        v[j] = (base + j < NSEG) ? counts[base + j] : 0;
        sum += v[j];
    }
    sdata[t] = sum;
    __syncthreads();
    for (int off = 1; off < 256; off <<= 1) {
        int xv = (t >= off) ? sdata[t - off] : 0;
        __syncthreads();
        sdata[t] += xv;
        __syncthreads();
    }
    int excl = (t == 0) ? 0 : sdata[t - 1];
    if (t == 255) blksums[blockIdx.x] = sdata[255];
    int run = excl;
#pragma unroll
    for (int j = 0; j < 8; ++j) {
        if (base + j < NSEG) offsets[base + j] = run;
        run += v[j];
    }
}

// Scan b: exclusive scan of the block sums (single block).
__global__ void k_scan_b(int* __restrict__ blksums) {
    __shared__ int s[128];
    int t = threadIdx.x;
    s[t] = (t < NSCAN_BLOCKS) ? blksums[t] : 0;
    __syncthreads();
    for (int off = 1; off < 128; off <<= 1) {
        int xv = (t >= off) ? s[t - off] : 0;
        __syncthreads();
        s[t] += xv;
        __syncthreads();
    }
    if (t < NSCAN_BLOCKS) blksums[t] = (t == 0) ? 0 : s[t - 1];
}

// Scan c: add block offsets; also copy into cursor.
__global__ void k_scan_c(int* __restrict__ offsets, int* __restrict__ cursor,
                         const int* __restrict__ blksums) {
    int i = blockIdx.x * 256 + threadIdx.x;
    if (i < NSEG) {
        int vv = offsets[i] + blksums[i >> 11];
        offsets[i] = vv;
        cursor[i] = vv;
    }
}

// Scatter: build CSR target lists; fused per-block exact edge-score max.
// Blocks are branch-uniform (N_EDGES % 256 == 0).
__global__ void k_scatter(const int* __restrict__ do_idx, const int* __restrict__ up_idx,
                          const float* __restrict__ s_src_irr, const float* __restrict__ s_tgt_irr,
                          const float* __restrict__ s_src_sol, const float* __restrict__ s_tgt_sol,
                          int* __restrict__ cursor, int* __restrict__ csr_tgt,
                          float* __restrict__ blockmax) {
    int tid = blockIdx.x * 256 + threadIdx.x;          // exact grid: 2*N_EDGES
    float ev;
    if (tid < N_EDGES) {
        int s = do_idx[tid], t = do_idx[N_EDGES + tid];
        int pos = atomicAdd(&cursor[s], 1);
        csr_tgt[pos] = t;
        ev = s_src_irr[s] + s_tgt_irr[t];
    } else {
        int e = tid - N_EDGES;
        int s = up_idx[e], t = up_idx[N_EDGES + e];
        int pos = atomicAdd(&cursor[N_CELLS + s], 1);
        csr_tgt[pos] = t;
        ev = s_src_sol[s] + s_tgt_sol[t];
    }
    ev = ev > 0.f ? ev : NEG_SLOPE * ev;
#pragma unroll
    for (int m = 32; m >= 1; m >>= 1) ev = fmaxf(ev, __shfl_xor(ev, m));
    __shared__ float sm[4];
    int lane = threadIdx.x & 63, w = threadIdx.x >> 6;
    if (lane == 0) sm[w] = ev;
    __syncthreads();
    if (threadIdx.x == 0)
        blockmax[blockIdx.x] = fmaxf(fmaxf(sm[0], sm[1]), fmaxf(sm[2], sm[3]));
}

// Reduce per-block maxes to the two global maxes (one block per branch).
__global__ void k_gmax_reduce(const float* __restrict__ blockmax, float* __restrict__ gmaxf) {
    int branch = blockIdx.x;
    const float* bm = blockmax + branch * BLOCKS_PER_BRANCH;
    float v = -INFINITY;
    for (int i = threadIdx.x; i < BLOCKS_PER_BRANCH; i += blockDim.x) v = fmaxf(v, bm[i]);
#pragma unroll
    for (int m = 32; m >= 1; m >>= 1) v = fmaxf(v, __shfl_xor(v, m));
    __shared__ float sm[4];
    int lane = threadIdx.x & 63, w = threadIdx.x >> 6;
    if (lane == 0) sm[w] = v;
    __syncthreads();
    if (threadIdx.x == 0)
        gmaxf[branch] = fmaxf(fmaxf(sm[0], sm[1]), fmaxf(sm[2], sm[3]));
}

// Final aggregate: one 64-lane wave per node; halves process alternating edges.
// num/den accumulated in registers; ELU fused; out written exactly once.
__global__ void k_node_aggregate(const int* __restrict__ csr_tgt,
                                 const int* __restrict__ offsets, const int* __restrict__ counts,
                                 const float* __restrict__ s_src_irr, const float* __restrict__ s_tgt_irr,
                                 const float* __restrict__ s_src_sol, const float* __restrict__ s_tgt_sol,
                                 const float* __restrict__ h_irr, const float* __restrict__ h_sol,
                                 const float* __restrict__ gmaxf,
                                 float* __restrict__ out) {
    int wave_in_block = threadIdx.x >> 6;
    int lane = threadIdx.x & 63;
    int n = blockIdx.x * (blockDim.x >> 6) + wave_in_block;
    if (n >= N_CELLS) return;
    int f = lane & 31;
    int half = lane >> 5;
    float g0 = gmaxf[0], g1 = gmaxf[1];

    float num = 0.f, den = 0.f;
    {   // irr branch
        int beg = offsets[n], deg = counts[n];
        float ssrc = s_src_irr[n];
        for (int i = half; i < deg; i += 2) {
            int t = csr_tgt[beg + i];
            float ev = ssrc + s_tgt_irr[t];
            ev = ev > 0.f ? ev : NEG_SLOPE * ev;
            float w = expf(ev - g0);
            den += w;
            num += w * h_irr[(long long)t * FDIM + f];
        }
    }
    num += __shfl_xor(num, 32);
    den += __shfl_xor(den, 32);
    float res = num / (den + 1e-10f);

    num = 0.f; den = 0.f;
    {   // sol branch
        int beg = offsets[N_CELLS + n], deg = counts[N_CELLS + n];
        float ssrc = s_src_sol[n];
        for (int i = half; i < deg; i += 2) {
            int t = csr_tgt[beg + i];
            float ev = ssrc + s_tgt_sol[t];
            ev = ev > 0.f ? ev : NEG_SLOPE * ev;
            float w = expf(ev - g1);
            den += w;
            num += w * h_sol[(long long)t * FDIM + f];
        }
    }
    num += __shfl_xor(num, 32);
    den += __shfl_xor(den, 32);
    res += num / (den + 1e-10f);

    res = res > 0.f ? res : expf(res) - 1.f;   // ELU
    if (half == 0) out[(long long)n * FDIM + f] = res;
}

extern "C" void kernel_launch(void* const* d_in, const int* in_sizes, int n_in,
                              void* d_out, int out_size, void* d_ws, size_t ws_size,
                              hipStream_t stream) {
    const float* x = (const float*)d_in[0];
    const int* do_index = (const int*)d_in[1];
    const int* up_index = (const int*)d_in[2];
    const float* Wirr = (const float*)d_in[3];
    const float* Wsol = (const float*)d_in[4];
    const float* att_irr = (const float*)d_in[5];
    const float* att_sol = (const float*)d_in[6];
    float* out = (float*)d_out;

    // Workspace partition
    float* ws = (float*)d_ws;
    float* h_irr = ws;                                   // N*F
    float* h_sol = h_irr + (size_t)N_CELLS * FDIM;       // N*F
    float* s_src_irr = h_sol + (size_t)N_CELLS * FDIM;   // N
    float* s_tgt_irr = s_src_irr + N_CELLS;              // N
    float* s_src_sol = s_tgt_irr + N_CELLS;              // N
    float* s_tgt_sol = s_src_sol + N_CELLS;              // N
    float* gmaxf = s_tgt_sol + N_CELLS;                  // 2
    float* blockmax = gmaxf + 2;                         // EDGE_BLOCKS
    int* counts = (int*)(blockmax + EDGE_BLOCKS);        // NSEG
    int* offsets = counts + NSEG;                        // NSEG
    int* cursor = offsets + NSEG;                        // NSEG
    int* blksums = cursor + NSEG;                        // 128
    int* csr_tgt = blksums + 128;                        // 2*N_EDGES

    hipMemsetAsync(counts, 0, NSEG * sizeof(int), stream);

    // K1: h + scores
    hipLaunchKernelGGL(k_h_scores, dim3(N_CELLS / 8), dim3(256), 0, stream,
                       x, Wirr, Wsol, att_irr, att_sol,
                       h_irr, h_sol, s_src_irr, s_tgt_irr, s_src_sol, s_tgt_sol);

    // K2: histogram
    hipLaunchKernelGGL(k_count, dim3(EDGE_BLOCKS), dim3(256), 0, stream,
                       do_index, up_index, counts);

    // K3: exclusive scan of counts -> offsets (+cursor copy)
    hipLaunchKernelGGL(k_scan_a, dim3(NSCAN_BLOCKS), dim3(256), 0, stream,
                       counts, offsets, blksums);
    hipLaunchKernelGGL(k_scan_b, dim3(1), dim3(128), 0, stream, blksums);
    hipLaunchKernelGGL(k_scan_c, dim3((NSEG + 255) / 256), dim3(256), 0, stream,
                       offsets, cursor, blksums);

    // K4: scatter into CSR + per-block max
    hipLaunchKernelGGL(k_scatter, dim3(EDGE_BLOCKS), dim3(256), 0, stream,
                       do_index, up_index, s_src_irr, s_tgt_irr, s_src_sol, s_tgt_sol,
                       cursor, csr_tgt, blockmax);

    // K5: global max per branch
    hipLaunchKernelGGL(k_gmax_reduce, dim3(2), dim3(256), 0, stream, blockmax, gmaxf);

    // K6: per-node aggregate + ELU (4 waves/block -> exact grid)
    hipLaunchKernelGGL(k_node_aggregate, dim3(N_CELLS / 4), dim3(256), 0, stream,
                       csr_tgt, offsets, counts,
                       s_src_irr, s_tgt_irr, s_src_sol, s_tgt_sol,
                       h_irr, h_sol, gmaxf, out);
}